// Round 1
// baseline (414.485 us; speedup 1.0000x reference)
//
#include <hip/hip_runtime.h>

// ScaledDotProductAttention winner-take-all (B=16, Lq=Lk=2048, D=64, fp32).
// reference: attn = softmax(QK^T/8); mask = (attn == rowmax); attn *= mask;
//            output = attn @ V;  return (output, attn)
// Post-mask attn has ~1 nonzero/row -> compute QK^T + online top-2 + Z only,
// zero-fill attn region inline, scatter winners, output = p * v[winner(s)].

namespace {
constexpr int LQn = 2048, LKn = 2048, Dn = 64;
constexpr int QB  = 64;            // q rows per block
constexpr int KBt = 256;           // k rows per LDS tile
constexpr int NT  = 256;           // threads per block
constexpr int NTILES = LKn / KBt;  // 8
// e = exp(s - 10) computed as exp2(acc * (0.125*log2e) - 10*log2e)
constexpr float K1 = 0.125f * 1.44269504088896340736f;
constexpr float K2 = 10.0f  * 1.44269504088896340736f;
}

__global__ __launch_bounds__(NT, 2)
void attn_wta(const float* __restrict__ qg, const float* __restrict__ kg,
              const float* __restrict__ vg, float* __restrict__ out_o,
              float* __restrict__ out_a) {
  __shared__ float4 k_s[KBt][16];  // 64 KB, column-swizzled: [r][c4 ^ (r&7)]
  __shared__ float  q_s[QB][Dn];   // 16 KB; reused after k-loop for row stats
  float* rowP  = &q_s[0][0];       // overlay (used only after final barrier)
  int*   rPos1 = (int*)&q_s[1][0];
  int*   rPos2 = (int*)&q_s[2][0];

  const int t  = threadIdx.x;
  const int tx = t & 31;           // 32 threads share a q-row group
  const int ty = t >> 5;           // 8 row-groups of 8 rows

  // XCD-bijective swizzle (512 % 8 == 0): each XCD gets 64 consecutive wgs
  // = 2 full batches -> k panel (512 KB) stays L2-local.
  const int wg  = (int)blockIdx.x;
  const int swz = (wg & 7) * 64 + (wg >> 3);
  const int bb  = swz >> 5;         // batch
  const int q0  = (swz & 31) * QB;  // q-tile base row

  const float* qb = qg + ((size_t)bb * LQn + q0) * Dn;
  const float* kb = kg + (size_t)bb * LKn * Dn;
  const float* vb = vg + (size_t)bb * LKn * Dn;
  float* oa = out_a + ((size_t)bb * LQn + q0) * (size_t)LKn;
  float* oo = out_o + ((size_t)bb * LQn + q0) * Dn;

  // ---- stage q tile (64 rows x 16 float4), unswizzled (reads broadcast) ----
  #pragma unroll
  for (int it = 0; it < 4; ++it) {
    int slot = it * NT + t;
    int r = slot >> 4, c4 = slot & 15;
    float4 val = *(const float4*)(qb + r * Dn + c4 * 4);
    *(float4*)&q_s[r][c4 * 4] = val;
  }

  // per-thread online stats for 8 rows: top-2 (e,pos) + Z partial
  float emax[8], e2nd[8], zsum[8];
  int   pos1[8], pos2[8];
  #pragma unroll
  for (int i = 0; i < 8; ++i) {
    emax[i] = -1.0f; e2nd[i] = -1.0f; zsum[i] = 0.0f; pos1[i] = 0; pos2[i] = 0;
  }

  // zero-store base: thread owns row (t>>6)+4*it, cols (t&63)*4 .. +3
  float* zbase = oa + (size_t)(t >> 6) * LKn + (t & 63) * 4;

  #pragma unroll 1
  for (int kt = 0; kt < NTILES; ++kt) {
    __syncthreads();  // protect k_s from previous tile's readers
    // ---- stage k tile: 256 rows x 16 float4, swizzled ----
    const float* ksrc = kb + (size_t)kt * KBt * Dn;
    #pragma unroll
    for (int it = 0; it < 16; ++it) {
      int slot = it * NT + t;
      int r = slot >> 4, c4 = slot & 15;
      float4 val = *(const float4*)(ksrc + r * Dn + c4 * 4);
      k_s[r][c4 ^ (r & 7)] = val;
    }
    __syncthreads();

    // ---- zero-fill attn chunk [64 rows][256 cols]; drains under compute ----
    {
      float4 z4 = make_float4(0.f, 0.f, 0.f, 0.f);
      float* zp = zbase + (size_t)kt * KBt;
      #pragma unroll
      for (int it = 0; it < 16; ++it)
        *(float4*)(zp + (size_t)it * 4 * LKn) = z4;
    }

    // ---- 64x256 tile of QK^T: 8x8 per thread, fp32 FMA ----
    float acc[8][8];
    #pragma unroll
    for (int i = 0; i < 8; ++i)
      #pragma unroll
      for (int j = 0; j < 8; ++j) acc[i][j] = 0.0f;

    #pragma unroll 4
    for (int dc = 0; dc < 16; ++dc) {
      float4 qv[8], kv[8];
      #pragma unroll
      for (int i = 0; i < 8; ++i)
        qv[i] = *(const float4*)&q_s[ty * 8 + i][dc * 4];
      const int csw = dc ^ (tx & 7);  // (j*32+tx)&7 == tx&7
      #pragma unroll
      for (int j = 0; j < 8; ++j)
        kv[j] = k_s[j * 32 + tx][csw];
      #pragma unroll
      for (int i = 0; i < 8; ++i)
        #pragma unroll
        for (int j = 0; j < 8; ++j) {
          acc[i][j] = fmaf(qv[i].x, kv[j].x, acc[i][j]);
          acc[i][j] = fmaf(qv[i].y, kv[j].y, acc[i][j]);
          acc[i][j] = fmaf(qv[i].z, kv[j].z, acc[i][j]);
          acc[i][j] = fmaf(qv[i].w, kv[j].w, acc[i][j]);
        }
    }

    // ---- fold tile into online stats ----
    const int kt0 = kt * KBt;
    #pragma unroll
    for (int i = 0; i < 8; ++i) {
      float em = emax[i], es = e2nd[i], zz = zsum[i];
      int p1 = pos1[i], p2 = pos2[i];
      #pragma unroll
      for (int j = 0; j < 8; ++j) {
        float e = exp2f(fmaf(acc[i][j], K1, -K2));
        int pos = kt0 + j * 32 + tx;
        bool g1 = e > em, g2 = e > es;
        es = g1 ? em : (g2 ? e : es);
        p2 = g1 ? p1 : (g2 ? pos : p2);
        em = g1 ? e  : em;
        p1 = g1 ? pos : p1;
        zz += e;
      }
      emax[i] = em; e2nd[i] = es; zsum[i] = zz; pos1[i] = p1; pos2[i] = p2;
    }
  }

  // ---- reduce stats across the 32 threads sharing each row ----
  #pragma unroll
  for (int i = 0; i < 8; ++i) {
    float em = emax[i], es = e2nd[i], zz = zsum[i];
    int p1 = pos1[i], p2 = pos2[i];
    #pragma unroll
    for (int m = 16; m >= 1; m >>= 1) {   // masks <32 stay in 32-lane halves
      float oem = __shfl_xor(em, m);
      float oes = __shfl_xor(es, m);
      float ozz = __shfl_xor(zz, m);
      int   op1 = __shfl_xor(p1, m);
      int   op2 = __shfl_xor(p2, m);
      zz += ozz;
      // merge partner's top-2: insert (oem,op1), then (oes,op2)
      bool g1 = oem > em, g2 = oem > es;
      es = g1 ? em : (g2 ? oem : es);
      p2 = g1 ? p1 : (g2 ? op1 : p2);
      em = g1 ? oem : em;
      p1 = g1 ? op1 : p1;
      bool h2 = oes > es;                 // oes <= new em always
      es = h2 ? oes : es;
      p2 = h2 ? op2 : p2;
    }
    emax[i] = em; e2nd[i] = es; zsum[i] = zz; pos1[i] = p1; pos2[i] = p2;
  }

  __syncthreads();  // all q_s reads done; all zero-stores drained

  if (tx == 0) {
    #pragma unroll
    for (int i = 0; i < 8; ++i) {
      int r = ty * 8 + i;
      float p  = emax[i] / zsum[i];
      float p2 = e2nd[i] / zsum[i];
      rowP[r]  = p;
      rPos1[r] = pos1[i];
      rPos2[r] = (p2 == p) ? pos2[i] : -1;  // prob-level tie like reference
    }
  }
  __syncthreads();

  // ---- winner scatter into attn (ordered after zero-fill by barrier) ----
  if (t < QB) {
    float p = rowP[t];
    float* ar = oa + (size_t)t * LKn;
    ar[rPos1[t]] = p;
    int w2 = rPos2[t];
    if (w2 >= 0) ar[w2] = p;
  }

  // ---- output rows: out[r,:] = p * v[w1,:] (+ p * v[w2,:]) ----
  #pragma unroll
  for (int it = 0; it < 4; ++it) {
    int slot = it * NT + t;
    int r = slot >> 4, c4 = slot & 15;
    float p = rowP[r];
    int w1 = rPos1[r], w2 = rPos2[r];
    const float4 v1 = *(const float4*)(vb + (size_t)w1 * Dn + c4 * 4);
    float4 o;
    o.x = p * v1.x; o.y = p * v1.y; o.z = p * v1.z; o.w = p * v1.w;
    if (w2 >= 0) {
      const float4 v2 = *(const float4*)(vb + (size_t)w2 * Dn + c4 * 4);
      o.x += p * v2.x; o.y += p * v2.y; o.z += p * v2.z; o.w += p * v2.w;
    }
    *(float4*)(oo + (size_t)r * Dn + c4 * 4) = o;
  }
}

extern "C" void kernel_launch(void* const* d_in, const int* in_sizes, int n_in,
                              void* d_out, int out_size, void* d_ws, size_t ws_size,
                              hipStream_t stream) {
  const float* q = (const float*)d_in[0];
  const float* k = (const float*)d_in[1];
  const float* v = (const float*)d_in[2];
  float* out_o = (float*)d_out;                                   // [16,2048,64]
  float* out_a = (float*)d_out + (size_t)16 * 2048 * 64;          // [16,2048,2048]
  hipLaunchKernelGGL(attn_wta, dim3(16 * (LQn / QB)), dim3(NT), 0, stream,
                     q, k, v, out_o, out_a);
}